// Round 1
// baseline (217.585 us; speedup 1.0000x reference)
//
#include <hip/hip_runtime.h>
#include <hip/hip_bf16.h>

#define B_DIM   1024
#define N_DIM   2048
#define G_DIM   32
#define H1_DIM  2048
#define H2_DIM  512
#define BN_EPS  1e-5f
#define SLOPE   0.05f

typedef short v8s __attribute__((ext_vector_type(8)));
typedef float v4f __attribute__((ext_vector_type(4)));

__device__ __forceinline__ float lrelu_f(float v) { return v >= 0.f ? v : SLOPE * v; }

// ---------------------------------------------------------------- softmax(att_w)
__global__ __launch_bounds__(256) void softmax_kernel(const float* __restrict__ w,
                                                      float* __restrict__ att) {
    __shared__ float red[8];
    int t = threadIdx.x;
    float vals[8];
    float m = -1e30f;
#pragma unroll
    for (int i = 0; i < 8; ++i) { vals[i] = w[t + i * 256]; m = fmaxf(m, vals[i]); }
#pragma unroll
    for (int off = 32; off; off >>= 1) m = fmaxf(m, __shfl_down(m, off, 64));
    if ((t & 63) == 0) red[t >> 6] = m;
    __syncthreads();
    float M = fmaxf(fmaxf(red[0], red[1]), fmaxf(red[2], red[3]));
    float s = 0.f;
#pragma unroll
    for (int i = 0; i < 8; ++i) { vals[i] = expf(vals[i] - M); s += vals[i]; }
#pragma unroll
    for (int off = 32; off; off >>= 1) s += __shfl_down(s, off, 64);
    if ((t & 63) == 0) red[4 + (t >> 6)] = s;
    __syncthreads();
    float inv = 1.f / (red[4] + red[5] + red[6] + red[7]);
#pragma unroll
    for (int i = 0; i < 8; ++i) att[t + i * 256] = vals[i] * inv;
}

// ------------------------------------------- W [Kd][Jd] f32 -> Wt [Jd][Kd] bf16, optional row scale[k]
__global__ __launch_bounds__(256) void convert_transpose(const float* __restrict__ W,
                                                         const float* __restrict__ scale,
                                                         __hip_bfloat16* __restrict__ Wt,
                                                         int Kd, int Jd) {
    __shared__ float tile[64][65];
    int t = threadIdx.x;
    int j0 = blockIdx.x * 64, k0 = blockIdx.y * 64;
#pragma unroll
    for (int p = 0; p < 16; ++p) {
        int r = (t >> 6) + p * 4;          // row within k-tile
        int k = k0 + r;
        float v = W[(size_t)k * Jd + j0 + (t & 63)];
        if (scale) v *= scale[k];
        tile[r][t & 63] = v;
    }
    __syncthreads();
#pragma unroll
    for (int p = 0; p < 8; ++p) {
        int jr = (t >> 5) + p * 8;         // row within j-tile
        int kc = (t & 31) * 2;
        __hip_bfloat16 v0 = __float2bfloat16(tile[kc][jr]);
        __hip_bfloat16 v1 = __float2bfloat16(tile[kc + 1][jr]);
        ushort2 pk;
        pk.x = *(unsigned short*)&v0;
        pk.y = *(unsigned short*)&v1;
        *(ushort2*)(Wt + (size_t)(j0 + jr) * Kd + k0 + kc) = pk;
    }
}

// ------------------------------------------------ g[b][n] = lrelu(dot(x[b,n*32:], Wg[n]) + bg[n])
__global__ __launch_bounds__(256) void group_linear(const float* __restrict__ x,
                                                    const float* __restrict__ Wg,
                                                    const float* __restrict__ bg,
                                                    __hip_bfloat16* __restrict__ g) {
    __shared__ float wgs[256 * 33];
    int t = threadIdx.x;
    int n0 = blockIdx.x * 256;
    const float4* src = (const float4*)(Wg + (size_t)n0 * 32);
#pragma unroll
    for (int i = 0; i < 8; ++i) {
        float4 v = src[t + i * 256];
        int e = (t + i * 256) * 4;
        int n = e >> 5, kk = e & 31;
        wgs[n * 33 + kk + 0] = v.x;
        wgs[n * 33 + kk + 1] = v.y;
        wgs[n * 33 + kk + 2] = v.z;
        wgs[n * 33 + kk + 3] = v.w;
    }
    float bgv = bg[n0 + t];
    __syncthreads();
#pragma unroll
    for (int bb = 0; bb < 4; ++bb) {
        int b = blockIdx.y * 4 + bb;
        const float4* xr = (const float4*)(x + (size_t)b * (N_DIM * G_DIM) + (size_t)(n0 + t) * 32);
        float s = 0.f;
#pragma unroll
        for (int i = 0; i < 8; ++i) {
            float4 v = xr[i];
            s += v.x * wgs[t * 33 + i * 4 + 0];
            s += v.y * wgs[t * 33 + i * 4 + 1];
            s += v.z * wgs[t * 33 + i * 4 + 2];
            s += v.w * wgs[t * 33 + i * 4 + 3];
        }
        s = lrelu_f(s + bgv);
        g[(size_t)b * N_DIM + n0 + t] = __float2bfloat16(s);
    }
}

// ------------------------------------------------ C[M][N] f32 = A[M][K]bf16 @ Bt[N][K]bf16^T
__global__ __launch_bounds__(256) void gemm_bf16_tn(const __hip_bfloat16* __restrict__ A,
                                                    const __hip_bfloat16* __restrict__ Bt,
                                                    float* __restrict__ C,
                                                    int M, int N, int K) {
    int tid = threadIdx.x;
    int lane = tid & 63, wave = tid >> 6;
    int wr = wave >> 1, wc = wave & 1;
    int rbase = blockIdx.x * 64 + wr * 32;
    int cbase = blockIdx.y * 128 + wc * 64;
    int l15 = lane & 15, kh = (lane >> 4) * 8;

    const v8s* pa0 = (const v8s*)(A + (size_t)(rbase + l15) * K + kh);
    const v8s* pa1 = (const v8s*)(A + (size_t)(rbase + 16 + l15) * K + kh);
    const v8s* pb0 = (const v8s*)(Bt + (size_t)(cbase + l15) * K + kh);
    const v8s* pb1 = (const v8s*)(Bt + (size_t)(cbase + 16 + l15) * K + kh);
    const v8s* pb2 = (const v8s*)(Bt + (size_t)(cbase + 32 + l15) * K + kh);
    const v8s* pb3 = (const v8s*)(Bt + (size_t)(cbase + 48 + l15) * K + kh);

    v4f acc00 = {0.f, 0.f, 0.f, 0.f}, acc01 = acc00, acc02 = acc00, acc03 = acc00;
    v4f acc10 = acc00, acc11 = acc00, acc12 = acc00, acc13 = acc00;

    v8s a0 = pa0[0], a1 = pa1[0];
    v8s b0 = pb0[0], b1 = pb1[0], b2 = pb2[0], b3 = pb3[0];

    int nk = K >> 5;   // K/32 steps, each step advances 4 v8s
    for (int s = 1; s < nk; ++s) {
        v8s na0 = pa0[s * 4], na1 = pa1[s * 4];
        v8s nb0 = pb0[s * 4], nb1 = pb1[s * 4], nb2 = pb2[s * 4], nb3 = pb3[s * 4];
        acc00 = __builtin_amdgcn_mfma_f32_16x16x32_bf16(a0, b0, acc00, 0, 0, 0);
        acc01 = __builtin_amdgcn_mfma_f32_16x16x32_bf16(a0, b1, acc01, 0, 0, 0);
        acc02 = __builtin_amdgcn_mfma_f32_16x16x32_bf16(a0, b2, acc02, 0, 0, 0);
        acc03 = __builtin_amdgcn_mfma_f32_16x16x32_bf16(a0, b3, acc03, 0, 0, 0);
        acc10 = __builtin_amdgcn_mfma_f32_16x16x32_bf16(a1, b0, acc10, 0, 0, 0);
        acc11 = __builtin_amdgcn_mfma_f32_16x16x32_bf16(a1, b1, acc11, 0, 0, 0);
        acc12 = __builtin_amdgcn_mfma_f32_16x16x32_bf16(a1, b2, acc12, 0, 0, 0);
        acc13 = __builtin_amdgcn_mfma_f32_16x16x32_bf16(a1, b3, acc13, 0, 0, 0);
        a0 = na0; a1 = na1; b0 = nb0; b1 = nb1; b2 = nb2; b3 = nb3;
    }
    acc00 = __builtin_amdgcn_mfma_f32_16x16x32_bf16(a0, b0, acc00, 0, 0, 0);
    acc01 = __builtin_amdgcn_mfma_f32_16x16x32_bf16(a0, b1, acc01, 0, 0, 0);
    acc02 = __builtin_amdgcn_mfma_f32_16x16x32_bf16(a0, b2, acc02, 0, 0, 0);
    acc03 = __builtin_amdgcn_mfma_f32_16x16x32_bf16(a0, b3, acc03, 0, 0, 0);
    acc10 = __builtin_amdgcn_mfma_f32_16x16x32_bf16(a1, b0, acc10, 0, 0, 0);
    acc11 = __builtin_amdgcn_mfma_f32_16x16x32_bf16(a1, b1, acc11, 0, 0, 0);
    acc12 = __builtin_amdgcn_mfma_f32_16x16x32_bf16(a1, b2, acc12, 0, 0, 0);
    acc13 = __builtin_amdgcn_mfma_f32_16x16x32_bf16(a1, b3, acc13, 0, 0, 0);

    int crow = (lane >> 4) * 4;
#define WR_ACC(ACCV, FR, FC)                                                   \
    {                                                                          \
        int r = rbase + (FR) * 16 + crow;                                      \
        int c = cbase + (FC) * 16 + l15;                                       \
        C[(size_t)(r + 0) * N + c] = ACCV[0];                                  \
        C[(size_t)(r + 1) * N + c] = ACCV[1];                                  \
        C[(size_t)(r + 2) * N + c] = ACCV[2];                                  \
        C[(size_t)(r + 3) * N + c] = ACCV[3];                                  \
    }
    WR_ACC(acc00, 0, 0) WR_ACC(acc01, 0, 1) WR_ACC(acc02, 0, 2) WR_ACC(acc03, 0, 3)
    WR_ACC(acc10, 1, 0) WR_ACC(acc11, 1, 1) WR_ACC(acc12, 1, 2) WR_ACC(acc13, 1, 3)
#undef WR_ACC
}

// ------------------------------------------------ column partial sums over a slice of rows
__global__ __launch_bounds__(256) void col_partial(const float* __restrict__ H,
                                                   float* __restrict__ ps, float* __restrict__ pq,
                                                   int C, int rows) {
    int c = blockIdx.x * 256 + threadIdx.x;
    int r0 = blockIdx.y * rows;
    float s = 0.f, q = 0.f;
    for (int r = 0; r < rows; ++r) {
        float v = H[(size_t)(r0 + r) * C + c];
        s += v;
        q += v * v;
    }
    ps[(size_t)blockIdx.y * C + c] = s;
    pq[(size_t)blockIdx.y * C + c] = q;
}

// ------------------------------------------------ finalize: scale = rstd*gamma, shift = beta - mu*scale
__global__ __launch_bounds__(256) void col_finalize(const float* __restrict__ ps,
                                                    const float* __restrict__ pq,
                                                    const float* __restrict__ gamma,
                                                    const float* __restrict__ beta,
                                                    float* __restrict__ scale,
                                                    float* __restrict__ shift,
                                                    int C, int nsplit, float invB) {
    int c = blockIdx.x * 256 + threadIdx.x;
    if (c >= C) return;
    float s = 0.f, q = 0.f;
    for (int i = 0; i < nsplit; ++i) {
        s += ps[(size_t)i * C + c];
        q += pq[(size_t)i * C + c];
    }
    float mu = s * invB;
    float var = q * invB - mu * mu;
    var = fmaxf(var, 0.f);
    float rs = rsqrtf(var + BN_EPS);
    float sc = rs * gamma[c];
    scale[c] = sc;
    shift[c] = beta[c] - mu * sc;
}

// ------------------------------------------------ h = bf16(lrelu(hraw*scale + shift))
__global__ __launch_bounds__(256) void bn_apply(const float* __restrict__ hraw,
                                                const float* __restrict__ scale,
                                                const float* __restrict__ shift,
                                                __hip_bfloat16* __restrict__ o, int Cmask) {
    size_t idx = ((size_t)blockIdx.x * 256 + threadIdx.x) * 4;
    int j = (int)(idx & (size_t)Cmask);
    float4 v = *(const float4*)(hraw + idx);
    float4 sc = *(const float4*)(scale + j);
    float4 sh = *(const float4*)(shift + j);
    float r0 = lrelu_f(v.x * sc.x + sh.x);
    float r1 = lrelu_f(v.y * sc.y + sh.y);
    float r2 = lrelu_f(v.z * sc.z + sh.z);
    float r3 = lrelu_f(v.w * sc.w + sh.w);
    __hip_bfloat16 o0 = __float2bfloat16(r0), o1 = __float2bfloat16(r1);
    __hip_bfloat16 o2 = __float2bfloat16(r2), o3 = __float2bfloat16(r3);
    ushort4 pk;
    pk.x = *(unsigned short*)&o0; pk.y = *(unsigned short*)&o1;
    pk.z = *(unsigned short*)&o2; pk.w = *(unsigned short*)&o3;
    *(ushort4*)(o + idx) = pk;
}

// ------------------------------------------------ out[b] = sum_j lrelu(bn(h2raw[b,j])) * Wo[j] + bo
__global__ __launch_bounds__(256) void bn_dot_out(const float* __restrict__ h2,
                                                  const float* __restrict__ scale2,
                                                  const float* __restrict__ shift2,
                                                  const float* __restrict__ Wo,
                                                  const float* __restrict__ bo,
                                                  float* __restrict__ out) {
    __shared__ float red[4];
    int b = blockIdx.x, t = threadIdx.x;
    float s = 0.f;
#pragma unroll
    for (int p = 0; p < 2; ++p) {
        int j = t + p * 256;
        float v = lrelu_f(h2[(size_t)b * H2_DIM + j] * scale2[j] + shift2[j]);
        s += v * Wo[j];
    }
#pragma unroll
    for (int off = 32; off; off >>= 1) s += __shfl_down(s, off, 64);
    if ((t & 63) == 0) red[t >> 6] = s;
    __syncthreads();
    if (t == 0) out[b] = red[0] + red[1] + red[2] + red[3] + bo[0];
}

// ================================================================ host
extern "C" void kernel_launch(void* const* d_in, const int* in_sizes, int n_in,
                              void* d_out, int out_size, void* d_ws, size_t ws_size,
                              hipStream_t stream) {
    const float* x     = (const float*)d_in[0];
    const float* Wg    = (const float*)d_in[1];
    const float* bg    = (const float*)d_in[2];
    const float* att_w = (const float*)d_in[3];
    const float* W1    = (const float*)d_in[4];
    const float* gamma1 = (const float*)d_in[6];
    const float* beta1  = (const float*)d_in[7];
    const float* W2    = (const float*)d_in[8];
    const float* gamma2 = (const float*)d_in[10];
    const float* beta2  = (const float*)d_in[11];
    const float* Wo    = (const float*)d_in[12];
    const float* bo    = (const float*)d_in[13];
    float* out = (float*)d_out;

    char* ws = (char*)d_ws;
    size_t off = 0;
    auto alloc = [&](size_t bytes) {
        void* p = ws + off;
        off = (off + bytes + 255) & ~(size_t)255;
        return p;
    };
    float*          att    = (float*)alloc(N_DIM * 4);
    __hip_bfloat16* W1T    = (__hip_bfloat16*)alloc((size_t)H1_DIM * N_DIM * 2);
    __hip_bfloat16* W2T    = (__hip_bfloat16*)alloc((size_t)H2_DIM * H1_DIM * 2);
    __hip_bfloat16* g      = (__hip_bfloat16*)alloc((size_t)B_DIM * N_DIM * 2);
    float*          h1raw  = (float*)alloc((size_t)B_DIM * H1_DIM * 4);
    __hip_bfloat16* h1     = (__hip_bfloat16*)alloc((size_t)B_DIM * H1_DIM * 2);
    float*          h2raw  = (float*)alloc((size_t)B_DIM * H2_DIM * 4);
    float*          ps     = (float*)alloc(32 * H1_DIM * 4);
    float*          pq     = (float*)alloc(32 * H1_DIM * 4);
    float*          scale1 = (float*)alloc(H1_DIM * 4);
    float*          shift1 = (float*)alloc(H1_DIM * 4);
    float*          scale2 = (float*)alloc(H2_DIM * 4);
    float*          shift2 = (float*)alloc(H2_DIM * 4);
    (void)ws_size; (void)in_sizes; (void)n_in; (void)out_size;

    // 1. softmax of attention weights
    softmax_kernel<<<1, 256, 0, stream>>>(att_w, att);
    // 2. W1T[j][k] = bf16(att[k] * W1[k][j]); W2T[j][k] = bf16(W2[k][j])
    convert_transpose<<<dim3(H1_DIM / 64, N_DIM / 64), 256, 0, stream>>>(W1, att, W1T, N_DIM, H1_DIM);
    convert_transpose<<<dim3(H2_DIM / 64, H1_DIM / 64), 256, 0, stream>>>(W2, nullptr, W2T, H1_DIM, H2_DIM);
    // 3. per-group linear + lrelu  -> g bf16 [B, N]
    group_linear<<<dim3(N_DIM / 256, B_DIM / 4), 256, 0, stream>>>(x, Wg, bg, g);
    // 4. GEMM1: h1raw = g @ (att*W1)
    gemm_bf16_tn<<<dim3(B_DIM / 64, H1_DIM / 128), 256, 0, stream>>>(g, W1T, h1raw, B_DIM, H1_DIM, N_DIM);
    // 5. BN1 stats -> scale1/shift1
    col_partial<<<dim3(H1_DIM / 256, 32), 256, 0, stream>>>(h1raw, ps, pq, H1_DIM, B_DIM / 32);
    col_finalize<<<dim3(H1_DIM / 256), 256, 0, stream>>>(ps, pq, gamma1, beta1, scale1, shift1,
                                                         H1_DIM, 32, 1.f / B_DIM);
    // 6. apply BN1 + lrelu -> h1 bf16
    bn_apply<<<dim3((B_DIM * H1_DIM) / (256 * 4)), 256, 0, stream>>>(h1raw, scale1, shift1, h1, H1_DIM - 1);
    // 7. GEMM2: h2raw = h1 @ W2
    gemm_bf16_tn<<<dim3(B_DIM / 64, H2_DIM / 128), 256, 0, stream>>>(h1, W2T, h2raw, B_DIM, H2_DIM, H1_DIM);
    // 8. BN2 stats -> scale2/shift2
    col_partial<<<dim3(H2_DIM / 256, 32), 256, 0, stream>>>(h2raw, ps, pq, H2_DIM, B_DIM / 32);
    col_finalize<<<dim3((H2_DIM + 255) / 256), 256, 0, stream>>>(ps, pq, gamma2, beta2, scale2, shift2,
                                                                 H2_DIM, 32, 1.f / B_DIM);
    // 9. BN2 + lrelu + dot(Wo) + bo -> out [B]
    bn_dot_out<<<dim3(B_DIM), 256, 0, stream>>>(h2raw, scale2, shift2, Wo, bo, out);
}